// Round 2
// baseline (256.933 us; speedup 1.0000x reference)
//
#include <hip/hip_runtime.h>
#include <hip/hip_bf16.h>

// SE3 equivariant cross attention, MI355X gfx950. Round 2.
//  - attn: 8-wave blocks (head x 2 j-subtiles), LDS merge of subtile partials,
//    v_cvt_pk_bf16_f32 for hot-loop bf16 packing. 16 waves/CU (was 8).
//  - prep: one fused kernel = bf16 casts + LDS-tiled weight transposes +
//    wave-parallel edge-bias table (was an 8-block latency bomb).
//  - K/V projections fused, sharing A traffic; V^T via swapped MFMA operands
//    so stores are coalesced.

#define NLIG   1024
#define NPOCK  8192
#define HIDDEN 256
#define ADIM   512
#define NHEAD  4
#define HDIM   64
#define NTAB   1024
#define NSPLIT 16
#define CHUNK  (NPOCK / NSPLIT)   // 512
#define LOG2E  1.4426950408889634f
#define QK_SCALE (0.125f * LOG2E) // 1/sqrt(64) * log2(e)

typedef float f32x16 __attribute__((ext_vector_type(16)));
typedef short short8 __attribute__((ext_vector_type(8)));

union U4S8 { uint4 u; short8 s; };

static __device__ __forceinline__ float exp2h(float x) {
  float r; asm("v_exp_f32 %0, %1" : "=v"(r) : "v"(x)); return r;
}
static __device__ __forceinline__ float rsqh(float x) {
  float r; asm("v_rsq_f32 %0, %1" : "=v"(r) : "v"(x)); return r;
}
static __device__ __forceinline__ unsigned cvtpk(float lo, float hi) {
  unsigned r;
  asm("v_cvt_pk_bf16_f32 %0, %1, %2" : "=v"(r) : "v"(lo), "v"(hi));
  return r;
}
static __device__ __forceinline__ unsigned short f2bf(float f) {
  union { __hip_bfloat16 h; unsigned short u; } c;
  c.h = __float2bfloat16(f);
  return c.u;
}
static __device__ __forceinline__ float bf2f(unsigned u16) {
  union { unsigned uu; float f; } c;
  c.uu = u16 << 16;
  return c.f;
}
static __device__ __forceinline__ short8 load_bf8(const unsigned short* p) {
  U4S8 t; t.u = *(const uint4*)p; return t.s;
}
static __device__ __forceinline__ f32x16 mfma32(short8 a, short8 b, f32x16 c) {
  return __builtin_amdgcn_mfma_f32_32x32x16_bf16(a, b, c, 0, 0, 0);
}

// ---------------- prep: casts + weight transposes + edge table --------------
// blocks [0,4352): bf16 casts  [4352,4800): 32x32 LDS transposes
// [4800,5056): edge table (wave per entry)
#define NCAST 4352
#define NTRANS 448
__global__ __launch_bounds__(256)
void prep_kernel(const float* __restrict__ hA, const float* __restrict__ hl,
                 const float* __restrict__ qw, const float* __restrict__ kw,
                 const float* __restrict__ vw, const float* __restrict__ ow,
                 const float* __restrict__ c1w,
                 const float* __restrict__ e1w, const float* __restrict__ e1b,
                 const float* __restrict__ e2w, const float* __restrict__ e2b,
                 unsigned short* __restrict__ hAb, unsigned short* __restrict__ hlb,
                 unsigned short* __restrict__ qwT, unsigned short* __restrict__ kwT,
                 unsigned short* __restrict__ vwT, unsigned short* __restrict__ owT,
                 unsigned short* __restrict__ c1wT, float* __restrict__ tabG) {
  int bx = blockIdx.x;
  int tid = threadIdx.x;
  if (bx < NCAST) {
    int id = bx * 256 + tid;
    const int nA4 = NPOCK * ADIM / 4;
    if (id < nA4) {
      float4 v = ((const float4*)hA)[id];
      ushort4 o; o.x = f2bf(v.x); o.y = f2bf(v.y); o.z = f2bf(v.z); o.w = f2bf(v.w);
      ((ushort4*)hAb)[id] = o;
    } else {
      int j = id - nA4;
      float4 v = ((const float4*)hl)[j];
      ushort4 o; o.x = f2bf(v.x); o.y = f2bf(v.y); o.z = f2bf(v.z); o.w = f2bf(v.w);
      ((ushort4*)hlb)[j] = o;
    }
  } else if (bx < NCAST + NTRANS) {
    int b = bx - NCAST;
    const float* src; unsigned short* dst; int K;
    if (b < 64)       { src = qw;  dst = qwT;  K = 256; }
    else if (b < 192) { src = kw;  dst = kwT;  K = 512; b -= 64; }
    else if (b < 320) { src = vw;  dst = vwT;  K = 512; b -= 192; }
    else if (b < 384) { src = ow;  dst = owT;  K = 256; b -= 320; }
    else              { src = c1w; dst = c1wT; K = 256; b -= 384; }
    int kt = K / 32;
    int k0 = (b % kt) * 32, n0 = (b / kt) * 32;
    __shared__ float tile[32][33];
    int tx = tid & 31, ty = tid >> 5;
#pragma unroll
    for (int r = 0; r < 4; ++r)
      tile[ty + 8 * r][tx] = src[(k0 + ty + 8 * r) * 256 + n0 + tx];
    __syncthreads();
#pragma unroll
    for (int r = 0; r < 4; ++r)
      dst[(n0 + ty + 8 * r) * K + k0 + tx] = f2bf(tile[tx][ty + 8 * r]);
  } else {
    int eb = bx - (NCAST + NTRANS);
    int w = tid >> 6, l = tid & 63;
    int entry = eb * 4 + w;
    float d = (entry + 0.5f) * (10.0f / NTAB);
    float a0 = 0.f, a1 = 0.f, a2 = 0.f, a3 = 0.f;
#pragma unroll
    for (int jj = 0; jj < 4; ++jj) {
      int j = l + jj * 64;
      float v = fmaf(d, e1w[j], e1b[j]);
      float s = v / (1.0f + __expf(-v));
      float4 w2 = ((const float4*)e2w)[j];
      a0 = fmaf(s, w2.x, a0);
      a1 = fmaf(s, w2.y, a1);
      a2 = fmaf(s, w2.z, a2);
      a3 = fmaf(s, w2.w, a3);
    }
#pragma unroll
    for (int m = 32; m >= 1; m >>= 1) {
      a0 += __shfl_xor(a0, m); a1 += __shfl_xor(a1, m);
      a2 += __shfl_xor(a2, m); a3 += __shfl_xor(a3, m);
    }
    if (l == 0) {
      tabG[0 * NTAB + entry] = (a0 + e2b[0]) * LOG2E;
      tabG[1 * NTAB + entry] = (a1 + e2b[1]) * LOG2E;
      tabG[2 * NTAB + entry] = (a2 + e2b[2]) * LOG2E;
      tabG[3 * NTAB + entry] = (a3 + e2b[3]) * LOG2E;
    }
  }
}

// ------------- fused K/V projection: 4 waves, shared A ----------------------
__global__ __launch_bounds__(256)
void kv_gemm_kernel(const unsigned short* __restrict__ hAb,
                    const unsigned short* __restrict__ kwT, const unsigned short* __restrict__ vwT,
                    const float* __restrict__ kb, const float* __restrict__ vb,
                    unsigned short* __restrict__ Kb, unsigned short* __restrict__ VTb) {
  int tid = threadIdx.x;
  int w = tid >> 6, lane = tid & 63;
  int lo = lane & 31, hi = lane >> 5;
  int m0 = blockIdx.x * 128 + w * 32;
  int n0 = blockIdx.y * 32;
  const unsigned short* ap  = hAb + (size_t)(m0 + lo) * ADIM + hi * 8;
  const unsigned short* bkp = kwT + (size_t)(n0 + lo) * ADIM + hi * 8;
  const unsigned short* bvp = vwT + (size_t)(n0 + lo) * ADIM + hi * 8;
  f32x16 aK, aV;
#pragma unroll
  for (int i = 0; i < 16; ++i) { aK[i] = 0.f; aV[i] = 0.f; }
#pragma unroll 8
  for (int kk = 0; kk < ADIM / 16; ++kk) {
    short8 a  = load_bf8(ap + kk * 16);
    short8 bk = load_bf8(bkp + kk * 16);
    short8 bv = load_bf8(bvp + kk * 16);
    aK = mfma32(a, bk, aK);      // C[m][n]
    aV = mfma32(bv, a, aV);      // swapped: C[n][m] -> coalesced V^T store
  }
  int n = n0 + lo;
  float bnK = kb[n];
#pragma unroll
  for (int g = 0; g < 4; ++g) {
#pragma unroll
    for (int rr = 0; rr < 4; ++rr) {
      int r = g * 4 + rr;
      int row = g * 8 + hi * 4 + rr;
      Kb[(size_t)(m0 + row) * HIDDEN + n] = f2bf(aK[r] + bnK);
      int nv = n0 + row;
      VTb[(size_t)nv * NPOCK + m0 + lo] = f2bf(aV[r] + vb[nv]);
    }
  }
}

// ------------- one-wave 32x32 MFMA GEMM (small mats) ------------------------
// MODE 0: bf16 out row-major   MODE 2: f32 out + residual   MODE 3: silu bf16
template <int MODE>
__global__ __launch_bounds__(64)
void gemm32_kernel(const unsigned short* __restrict__ A, const unsigned short* __restrict__ BT,
                   const float* __restrict__ bias, void* __restrict__ out,
                   const float* __restrict__ resid, int M, int N, int K) {
  int lane = threadIdx.x;
  int lo = lane & 31, hi = lane >> 5;
  int m0 = blockIdx.x * 32, n0 = blockIdx.y * 32;
  const unsigned short* ap = A + (size_t)(m0 + lo) * K + hi * 8;
  const unsigned short* bp = BT + (size_t)(n0 + lo) * K + hi * 8;
  f32x16 acc;
#pragma unroll
  for (int i = 0; i < 16; ++i) acc[i] = 0.f;
  int nk = K / 16;
#pragma unroll 4
  for (int kk = 0; kk < nk; ++kk) {
    short8 a = load_bf8(ap + kk * 16);
    short8 b = load_bf8(bp + kk * 16);
    acc = mfma32(a, b, acc);
  }
  int n = n0 + lo;
  float bn = bias[n];
#pragma unroll
  for (int g = 0; g < 4; ++g) {
#pragma unroll
    for (int rr = 0; rr < 4; ++rr) {
      int r = g * 4 + rr;
      int m = m0 + g * 8 + hi * 4 + rr;
      float v = acc[r] + bn;
      if (MODE == 0) {
        ((unsigned short*)out)[(size_t)m * N + n] = f2bf(v);
      } else if (MODE == 2) {
        ((float*)out)[(size_t)m * N + n] = v + resid[(size_t)m * N + n];
      } else {
        float sg = v / (1.0f + exp2h(-LOG2E * v));
        ((unsigned short*)out)[(size_t)m * N + n] = f2bf(sg);
      }
    }
  }
}

// ------------- flash cross-attention with geometry --------------------------
// grid: 32 q-tiles * NSPLIT; block: 8 waves = 4 heads x 2 j-subtiles.
__global__ __launch_bounds__(512, 4)
void attn_kernel(const unsigned short* __restrict__ Qbf, const unsigned short* __restrict__ Kbf,
                 const unsigned short* __restrict__ VTbf,
                 const float* __restrict__ x_lig, const float* __restrict__ x_pocket,
                 const float* __restrict__ tabG,
                 float* __restrict__ partO, float4* __restrict__ partZC) {
  __shared__ float4 xch[CHUNK];                 // 8 KB
  __shared__ float tab[NHEAD][NTAB];            // 16 KB
  __shared__ unsigned Ocomb[NHEAD][32][32];     // 16 KB (bf16x2 merge buffer)
  __shared__ float Zc[NHEAD][4][32];            // 2 KB

  int tid = threadIdx.x;
  int wid = tid >> 6;
  int h = wid & 3, sj = wid >> 2;
  int lane = tid & 63;
  int lo = lane & 31, hi = lane >> 5;
  int qt = blockIdx.x & 31;
  int split = blockIdx.x >> 5;
  int q0 = qt * 32;
  int j0g = split * CHUNK;

  for (int i = tid; i < CHUNK; i += 512) {
    float x = x_pocket[(j0g + i) * 3 + 0];
    float y = x_pocket[(j0g + i) * 3 + 1];
    float z = x_pocket[(j0g + i) * 3 + 2];
    float4 v; v.x = x; v.y = y; v.z = z; v.w = 0.f;
    xch[i] = v;
  }
  for (int i = tid; i < NHEAD * NTAB; i += 512) ((float*)tab)[i] = tabG[i];
  __syncthreads();

  int q = q0 + lo;
  float xl0 = x_lig[q * 3 + 0];
  float xl1 = x_lig[q * 3 + 1];
  float xl2 = x_lig[q * 3 + 2];

  short8 qfr[4];
#pragma unroll
  for (int kk = 0; kk < 4; ++kk)
    qfr[kk] = load_bf8(Qbf + (size_t)q * HIDDEN + h * HDIM + kk * 16 + hi * 8);

  const unsigned short* kbase =
      Kbf + (size_t)(j0g + sj * 32 + lo) * HIDDEN + h * HDIM + hi * 8;

  f32x16 O0, O1;
#pragma unroll
  for (int i = 0; i < 16; ++i) { O0[i] = 0.f; O1[i] = 0.f; }
  float Z = 0.f, c0 = 0.f, c1 = 0.f, c2 = 0.f;

#pragma unroll 1
  for (int t = 0; t < CHUNK / 64; ++t) {
    int jb = t * 64 + sj * 32;
    f32x16 s;
#pragma unroll
    for (int i = 0; i < 16; ++i) s[i] = 0.f;
#pragma unroll
    for (int kk = 0; kk < 4; ++kk) {
      short8 a = load_bf8(kbase + (size_t)t * 64 * HIDDEN + kk * 16);
      s = mfma32(a, qfr[kk], s);
    }
    unsigned wp[8];
    float pprev = 0.f;
#pragma unroll
    for (int r = 0; r < 16; ++r) {
      int jl = (r & 3) + 8 * (r >> 2) + 4 * hi;
      float4 xp = xch[jb + jl];
      float dx = xp.x - xl0, dy = xp.y - xl1, dz = xp.z - xl2;
      float r2 = fmaf(dx, dx, fmaf(dy, dy, dz * dz));
      float r2c = fmaxf(r2, 1e-24f);
      float rinv = rsqh(r2c);
      float d = r2c * rinv;
      int idx = (int)(d * (NTAB / 10.0f));
      idx = idx > (NTAB - 1) ? (NTAB - 1) : idx;
      float b = tab[h][idx];
      float s2 = fmaf(s[r], QK_SCALE, b);
      float pe = (r2 < 100.0f) ? exp2h(s2) : 0.0f;
      Z += pe;
      float pr = pe * rinv;
      c0 = fmaf(pr, dx, c0);
      c1 = fmaf(pr, dy, c1);
      c2 = fmaf(pr, dz, c2);
      if (r & 1) wp[r >> 1] = cvtpk(pprev, pe); else pprev = pe;
    }
#pragma unroll
    for (int sub = 0; sub < 2; ++sub) {
      unsigned W0 = wp[sub * 4 + 0], W1 = wp[sub * 4 + 1];
      unsigned W2 = wp[sub * 4 + 2], W3 = wp[sub * 4 + 3];
      unsigned e01 = (unsigned)__shfl_xor((int)(hi ? W0 : W2), 32);
      unsigned e23 = (unsigned)__shfl_xor((int)(hi ? W1 : W3), 32);
      U4S8 pb;
      pb.u.x = hi ? e01 : W0;
      pb.u.y = hi ? e23 : W1;
      pb.u.z = hi ? W2 : e01;
      pb.u.w = hi ? W3 : e23;
      const unsigned short* vbase =
          VTbf + (size_t)(h * HDIM + lo) * NPOCK + j0g + jb + sub * 16 + hi * 8;
      short8 v0 = load_bf8(vbase);
      short8 v1 = load_bf8(vbase + (size_t)32 * NPOCK);
      O0 = mfma32(v0, pb.s, O0);
      O1 = mfma32(v1, pb.s, O1);
    }
  }

  // merge the two j-subtile waves of each head in LDS
  if (sj == 1) {
#pragma unroll
    for (int g = 0; g < 4; ++g) {
      int dp = g * 4 + hi * 2;
      Ocomb[h][dp][lo]      = cvtpk(O0[g * 4 + 0], O0[g * 4 + 1]);
      Ocomb[h][dp + 1][lo]  = cvtpk(O0[g * 4 + 2], O0[g * 4 + 3]);
      Ocomb[h][dp + 16][lo] = cvtpk(O1[g * 4 + 0], O1[g * 4 + 1]);
      Ocomb[h][dp + 17][lo] = cvtpk(O1[g * 4 + 2], O1[g * 4 + 3]);
    }
    float Zt = Z + __shfl_xor(Z, 32);
    float c0t = c0 + __shfl_xor(c0, 32);
    float c1t = c1 + __shfl_xor(c1, 32);
    float c2t = c2 + __shfl_xor(c2, 32);
    if (hi == 0) {
      Zc[h][0][lo] = Zt; Zc[h][1][lo] = c0t; Zc[h][2][lo] = c1t; Zc[h][3][lo] = c2t;
    }
  }
  __syncthreads();
  if (sj == 0) {
#pragma unroll
    for (int g = 0; g < 4; ++g) {
      int dp = g * 4 + hi * 2;
      unsigned u;
      u = Ocomb[h][dp][lo];      O0[g*4+0] += bf2f(u & 0xffffu); O0[g*4+1] += bf2f(u >> 16);
      u = Ocomb[h][dp + 1][lo];  O0[g*4+2] += bf2f(u & 0xffffu); O0[g*4+3] += bf2f(u >> 16);
      u = Ocomb[h][dp + 16][lo]; O1[g*4+0] += bf2f(u & 0xffffu); O1[g*4+1] += bf2f(u >> 16);
      u = Ocomb[h][dp + 17][lo]; O1[g*4+2] += bf2f(u & 0xffffu); O1[g*4+3] += bf2f(u >> 16);
    }
    float* po = partO + (size_t)(((q * NHEAD) + h) * NSPLIT + split) * HDIM;
#pragma unroll
    for (int g = 0; g < 4; ++g) {
      float4 s0; s0.x = O0[g*4+0]; s0.y = O0[g*4+1]; s0.z = O0[g*4+2]; s0.w = O0[g*4+3];
      *(float4*)(po + g * 8 + hi * 4) = s0;
      float4 s1; s1.x = O1[g*4+0]; s1.y = O1[g*4+1]; s1.z = O1[g*4+2]; s1.w = O1[g*4+3];
      *(float4*)(po + 32 + g * 8 + hi * 4) = s1;
    }
    float Zt = Z + __shfl_xor(Z, 32);
    float c0t = c0 + __shfl_xor(c0, 32);
    float c1t = c1 + __shfl_xor(c1, 32);
    float c2t = c2 + __shfl_xor(c2, 32);
    if (hi == 0) {
      float4 zc;
      zc.x = Zt + Zc[h][0][lo];
      zc.y = c0t + Zc[h][1][lo];
      zc.z = c1t + Zc[h][2][lo];
      zc.w = c2t + Zc[h][3][lo];
      partZC[((q * NHEAD) + h) * NSPLIT + split] = zc;
    }
  }
}

// ------------- combine splits -> h_attended (bf16) + coord messages ---------
__global__ __launch_bounds__(256)
void combine_kernel(const float* __restrict__ partO, const float4* __restrict__ partZC,
                    unsigned short* __restrict__ hattb, float* __restrict__ cmsg) {
  int q = blockIdx.x;
  int t = threadIdx.x;
  int h = t >> 6, dl = t & 63;
  float Zh = 0.f;
#pragma unroll
  for (int s = 0; s < NSPLIT; ++s) Zh += partZC[(q * NHEAD + h) * NSPLIT + s].x;
  float o = 0.f;
#pragma unroll
  for (int s = 0; s < NSPLIT; ++s) o += partO[(size_t)((q * NHEAD + h) * NSPLIT + s) * HDIM + dl];
  float inv = (Zh > 0.f) ? 1.0f / Zh : 0.f;
  hattb[(size_t)q * HIDDEN + h * HDIM + dl] = f2bf(o * inv);

  __shared__ float sm[NHEAD][3];
  if (t < NHEAD) {
    float zz = 0.f, a0 = 0.f, a1 = 0.f, a2 = 0.f;
    for (int s = 0; s < NSPLIT; ++s) {
      float4 v = partZC[(q * NHEAD + t) * NSPLIT + s];
      zz += v.x; a0 += v.y; a1 += v.z; a2 += v.w;
    }
    float iv = (zz > 0.f) ? 0.25f / zz : 0.f;
    sm[t][0] = a0 * iv; sm[t][1] = a1 * iv; sm[t][2] = a2 * iv;
  }
  __syncthreads();
  if (t < 3) cmsg[q * 3 + t] = sm[0][t] + sm[1][t] + sm[2][t] + sm[3][t];
}

// ------------- coord scale dot + x_out --------------------------------------
__global__ __launch_bounds__(64)
void coord_kernel(const unsigned short* __restrict__ c1out, const float* __restrict__ c2w,
                  const float* __restrict__ c2b, const float* __restrict__ cmsg,
                  const float* __restrict__ x_lig, float* __restrict__ x_out) {
  int q = blockIdx.x;
  int lane = threadIdx.x;
  const unsigned short* row = c1out + (size_t)q * HIDDEN + lane * 4;
  ushort4 tv = *(const ushort4*)row;
  float4 wv = *(const float4*)(c2w + lane * 4);
  float acc = bf2f(tv.x) * wv.x + bf2f(tv.y) * wv.y + bf2f(tv.z) * wv.z + bf2f(tv.w) * wv.w;
#pragma unroll
  for (int m = 32; m >= 1; m >>= 1) acc += __shfl_xor(acc, m);
  if (lane == 0) {
    float sc = acc + c2b[0];
    x_out[q * 3 + 0] = x_lig[q * 3 + 0] + sc * cmsg[q * 3 + 0];
    x_out[q * 3 + 1] = x_lig[q * 3 + 1] + sc * cmsg[q * 3 + 1];
    x_out[q * 3 + 2] = x_lig[q * 3 + 2] + sc * cmsg[q * 3 + 2];
  }
}

extern "C" void kernel_launch(void* const* d_in, const int* in_sizes, int n_in,
                              void* d_out, int out_size, void* d_ws, size_t ws_size,
                              hipStream_t stream) {
  const float* h_lig  = (const float*)d_in[0];
  const float* x_lig  = (const float*)d_in[1];
  const float* h_atom = (const float*)d_in[2];
  const float* x_pock = (const float*)d_in[3];
  const float* qw  = (const float*)d_in[4];
  const float* qb  = (const float*)d_in[5];
  const float* kw  = (const float*)d_in[6];
  const float* kb  = (const float*)d_in[7];
  const float* vw  = (const float*)d_in[8];
  const float* vb  = (const float*)d_in[9];
  const float* ow  = (const float*)d_in[10];
  const float* ob  = (const float*)d_in[11];
  const float* e1w = (const float*)d_in[12];
  const float* e1b = (const float*)d_in[13];
  const float* e2w = (const float*)d_in[14];
  const float* e2b = (const float*)d_in[15];
  const float* c1w = (const float*)d_in[16];
  const float* c1b = (const float*)d_in[17];
  const float* c2w = (const float*)d_in[18];
  const float* c2b = (const float*)d_in[19];

  char* w = (char*)d_ws;
  unsigned short* hAb  = (unsigned short*)w; w += (size_t)NPOCK * ADIM * 2;
  unsigned short* hlb  = (unsigned short*)w; w += (size_t)NLIG * HIDDEN * 2;
  unsigned short* qwT  = (unsigned short*)w; w += 256 * 256 * 2;
  unsigned short* kwT  = (unsigned short*)w; w += 256 * 512 * 2;
  unsigned short* vwT  = (unsigned short*)w; w += 256 * 512 * 2;
  unsigned short* owT  = (unsigned short*)w; w += 256 * 256 * 2;
  unsigned short* c1wT = (unsigned short*)w; w += 256 * 256 * 2;
  unsigned short* Qb   = (unsigned short*)w; w += (size_t)NLIG * HIDDEN * 2;
  unsigned short* Kb   = (unsigned short*)w; w += (size_t)NPOCK * HIDDEN * 2;
  unsigned short* VTb  = (unsigned short*)w; w += (size_t)HIDDEN * NPOCK * 2;
  float* tabG          = (float*)w;          w += NHEAD * NTAB * 4;
  float* partO         = (float*)w;          w += (size_t)NLIG * NHEAD * NSPLIT * HDIM * 4;
  float* partZC        = (float*)w;          w += (size_t)NLIG * NHEAD * NSPLIT * 4 * 4;
  unsigned short* hatt = (unsigned short*)w; w += (size_t)NLIG * HIDDEN * 2;
  unsigned short* c1o  = (unsigned short*)w; w += (size_t)NLIG * HIDDEN * 2;
  float* cmsg          = (float*)w;          w += (size_t)NLIG * 3 * 4;

  float* hout = (float*)d_out;
  float* xout = ((float*)d_out) + (size_t)NLIG * HIDDEN;

  prep_kernel<<<NCAST + NTRANS + 256, 256, 0, stream>>>(
      h_atom, h_lig, qw, kw, vw, ow, c1w, e1w, e1b, e2w, e2b,
      hAb, hlb, qwT, kwT, vwT, owT, c1wT, tabG);
  kv_gemm_kernel<<<dim3(NPOCK / 128, HIDDEN / 32), 256, 0, stream>>>(
      hAb, kwT, vwT, kb, vb, Kb, VTb);
  gemm32_kernel<0><<<dim3(NLIG / 32, HIDDEN / 32), 64, 0, stream>>>(
      hlb, qwT, qb, (void*)Qb, nullptr, NLIG, HIDDEN, HIDDEN);
  attn_kernel<<<32 * NSPLIT, 512, 0, stream>>>(Qb, Kb, VTb, x_lig, x_pock, tabG,
                                               partO, (float4*)partZC);
  combine_kernel<<<NLIG, 256, 0, stream>>>(partO, (const float4*)partZC, hatt, cmsg);
  gemm32_kernel<2><<<dim3(NLIG / 32, HIDDEN / 32), 64, 0, stream>>>(
      hatt, owT, ob, (void*)hout, h_lig, NLIG, HIDDEN, HIDDEN);
  gemm32_kernel<3><<<dim3(NLIG / 32, HIDDEN / 32), 64, 0, stream>>>(
      hatt, c1wT, c1b, (void*)c1o, nullptr, NLIG, HIDDEN, HIDDEN);
  coord_kernel<<<NLIG, 64, 0, stream>>>(c1o, c2w, c2b, cmsg, x_lig, xout);
}

// Round 6
// 208.654 us; speedup vs baseline: 1.2314x; 1.2314x over previous
//
#include <hip/hip_runtime.h>
#include <hip/hip_bf16.h>

// SE3 equivariant cross attention, MI355X gfx950. Round 3 (3rd resubmit; three
// GPUAcquisitionTimeouts — this kernel has never been benched).
//  - attn: revert to round-1 4-wave/88-VGPR structure (round-2 8-wave version
//    spilled: VGPR 64 + 200MB scratch traffic). Occupancy via grid instead:
//    NSPLIT 16->32 (1024 blocks). partO stored bf16 to keep partial traffic flat.
//  - NTAB 1024 (20KB LDS/block -> LDS allows 8 blocks/CU, VGPR allows 5).
//  - prep fusion + fused K/V projection kept from round 2.

#define NLIG   1024
#define NPOCK  8192
#define HIDDEN 256
#define ADIM   512
#define NHEAD  4
#define HDIM   64
#define NTAB   1024
#define NSPLIT 32
#define CHUNK  (NPOCK / NSPLIT)   // 256
#define LOG2E  1.4426950408889634f
#define QK_SCALE (0.125f * LOG2E) // 1/sqrt(64) * log2(e)

typedef float f32x16 __attribute__((ext_vector_type(16)));
typedef short short8 __attribute__((ext_vector_type(8)));

union U4S8 { uint4 u; short8 s; };

static __device__ __forceinline__ float exp2h(float x) {
  float r; asm("v_exp_f32 %0, %1" : "=v"(r) : "v"(x)); return r;
}
static __device__ __forceinline__ float rsqh(float x) {
  float r; asm("v_rsq_f32 %0, %1" : "=v"(r) : "v"(x)); return r;
}
static __device__ __forceinline__ unsigned cvtpk(float lo, float hi) {
  unsigned r;
  asm("v_cvt_pk_bf16_f32 %0, %1, %2" : "=v"(r) : "v"(lo), "v"(hi));
  return r;
}
static __device__ __forceinline__ unsigned short f2bf(float f) {
  union { __hip_bfloat16 h; unsigned short u; } c;
  c.h = __float2bfloat16(f);
  return c.u;
}
static __device__ __forceinline__ float bf2f(unsigned u16) {
  union { unsigned uu; float f; } c;
  c.uu = u16 << 16;
  return c.f;
}
static __device__ __forceinline__ short8 load_bf8(const unsigned short* p) {
  U4S8 t; t.u = *(const uint4*)p; return t.s;
}
static __device__ __forceinline__ f32x16 mfma32(short8 a, short8 b, f32x16 c) {
  return __builtin_amdgcn_mfma_f32_32x32x16_bf16(a, b, c, 0, 0, 0);
}

// ---------------- prep: casts + weight transposes + edge table --------------
#define NCAST 4352
#define NTRANS 448
__global__ __launch_bounds__(256)
void prep_kernel(const float* __restrict__ hA, const float* __restrict__ hl,
                 const float* __restrict__ qw, const float* __restrict__ kw,
                 const float* __restrict__ vw, const float* __restrict__ ow,
                 const float* __restrict__ c1w,
                 const float* __restrict__ e1w, const float* __restrict__ e1b,
                 const float* __restrict__ e2w, const float* __restrict__ e2b,
                 unsigned short* __restrict__ hAb, unsigned short* __restrict__ hlb,
                 unsigned short* __restrict__ qwT, unsigned short* __restrict__ kwT,
                 unsigned short* __restrict__ vwT, unsigned short* __restrict__ owT,
                 unsigned short* __restrict__ c1wT, float* __restrict__ tabG) {
  int bx = blockIdx.x;
  int tid = threadIdx.x;
  if (bx < NCAST) {
    int id = bx * 256 + tid;
    const int nA4 = NPOCK * ADIM / 4;
    if (id < nA4) {
      float4 v = ((const float4*)hA)[id];
      ushort4 o; o.x = f2bf(v.x); o.y = f2bf(v.y); o.z = f2bf(v.z); o.w = f2bf(v.w);
      ((ushort4*)hAb)[id] = o;
    } else {
      int j = id - nA4;
      float4 v = ((const float4*)hl)[j];
      ushort4 o; o.x = f2bf(v.x); o.y = f2bf(v.y); o.z = f2bf(v.z); o.w = f2bf(v.w);
      ((ushort4*)hlb)[j] = o;
    }
  } else if (bx < NCAST + NTRANS) {
    int b = bx - NCAST;
    const float* src; unsigned short* dst; int K;
    if (b < 64)       { src = qw;  dst = qwT;  K = 256; }
    else if (b < 192) { src = kw;  dst = kwT;  K = 512; b -= 64; }
    else if (b < 320) { src = vw;  dst = vwT;  K = 512; b -= 192; }
    else if (b < 384) { src = ow;  dst = owT;  K = 256; b -= 320; }
    else              { src = c1w; dst = c1wT; K = 256; b -= 384; }
    int kt = K / 32;
    int k0 = (b % kt) * 32, n0 = (b / kt) * 32;
    __shared__ float tile[32][33];
    int tx = tid & 31, ty = tid >> 5;
#pragma unroll
    for (int r = 0; r < 4; ++r)
      tile[ty + 8 * r][tx] = src[(k0 + ty + 8 * r) * 256 + n0 + tx];
    __syncthreads();
#pragma unroll
    for (int r = 0; r < 4; ++r)
      dst[(n0 + ty + 8 * r) * K + k0 + tx] = f2bf(tile[tx][ty + 8 * r]);
  } else {
    int eb = bx - (NCAST + NTRANS);
    int w = tid >> 6, l = tid & 63;
    int entry = eb * 4 + w;
    float d = (entry + 0.5f) * (10.0f / NTAB);
    float a0 = 0.f, a1 = 0.f, a2 = 0.f, a3 = 0.f;
#pragma unroll
    for (int jj = 0; jj < 4; ++jj) {
      int j = l + jj * 64;
      float v = fmaf(d, e1w[j], e1b[j]);
      float s = v / (1.0f + __expf(-v));
      float4 w2 = ((const float4*)e2w)[j];
      a0 = fmaf(s, w2.x, a0);
      a1 = fmaf(s, w2.y, a1);
      a2 = fmaf(s, w2.z, a2);
      a3 = fmaf(s, w2.w, a3);
    }
#pragma unroll
    for (int m = 32; m >= 1; m >>= 1) {
      a0 += __shfl_xor(a0, m); a1 += __shfl_xor(a1, m);
      a2 += __shfl_xor(a2, m); a3 += __shfl_xor(a3, m);
    }
    if (l == 0) {
      tabG[0 * NTAB + entry] = (a0 + e2b[0]) * LOG2E;
      tabG[1 * NTAB + entry] = (a1 + e2b[1]) * LOG2E;
      tabG[2 * NTAB + entry] = (a2 + e2b[2]) * LOG2E;
      tabG[3 * NTAB + entry] = (a3 + e2b[3]) * LOG2E;
    }
  }
}

// ------------- fused K/V projection: 4 waves, shared A ----------------------
__global__ __launch_bounds__(256)
void kv_gemm_kernel(const unsigned short* __restrict__ hAb,
                    const unsigned short* __restrict__ kwT, const unsigned short* __restrict__ vwT,
                    const float* __restrict__ kb, const float* __restrict__ vb,
                    unsigned short* __restrict__ Kb, unsigned short* __restrict__ VTb) {
  int tid = threadIdx.x;
  int w = tid >> 6, lane = tid & 63;
  int lo = lane & 31, hi = lane >> 5;
  int m0 = blockIdx.x * 128 + w * 32;
  int n0 = blockIdx.y * 32;
  const unsigned short* ap  = hAb + (size_t)(m0 + lo) * ADIM + hi * 8;
  const unsigned short* bkp = kwT + (size_t)(n0 + lo) * ADIM + hi * 8;
  const unsigned short* bvp = vwT + (size_t)(n0 + lo) * ADIM + hi * 8;
  f32x16 aK, aV;
#pragma unroll
  for (int i = 0; i < 16; ++i) { aK[i] = 0.f; aV[i] = 0.f; }
#pragma unroll 8
  for (int kk = 0; kk < ADIM / 16; ++kk) {
    short8 a  = load_bf8(ap + kk * 16);
    short8 bk = load_bf8(bkp + kk * 16);
    short8 bv = load_bf8(bvp + kk * 16);
    aK = mfma32(a, bk, aK);      // C[m][n]
    aV = mfma32(bv, a, aV);      // swapped: C[n][m] -> coalesced V^T store
  }
  int n = n0 + lo;
  float bnK = kb[n];
#pragma unroll
  for (int g = 0; g < 4; ++g) {
#pragma unroll
    for (int rr = 0; rr < 4; ++rr) {
      int r = g * 4 + rr;
      int row = g * 8 + hi * 4 + rr;
      Kb[(size_t)(m0 + row) * HIDDEN + n] = f2bf(aK[r] + bnK);
      int nv = n0 + row;
      VTb[(size_t)nv * NPOCK + m0 + lo] = f2bf(aV[r] + vb[nv]);
    }
  }
}

// ------------- one-wave 32x32 MFMA GEMM (small mats) ------------------------
// MODE 0: bf16 out row-major   MODE 2: f32 out + residual   MODE 3: silu bf16
template <int MODE>
__global__ __launch_bounds__(64)
void gemm32_kernel(const unsigned short* __restrict__ A, const unsigned short* __restrict__ BT,
                   const float* __restrict__ bias, void* __restrict__ out,
                   const float* __restrict__ resid, int M, int N, int K) {
  int lane = threadIdx.x;
  int lo = lane & 31, hi = lane >> 5;
  int m0 = blockIdx.x * 32, n0 = blockIdx.y * 32;
  const unsigned short* ap = A + (size_t)(m0 + lo) * K + hi * 8;
  const unsigned short* bp = BT + (size_t)(n0 + lo) * K + hi * 8;
  f32x16 acc;
#pragma unroll
  for (int i = 0; i < 16; ++i) acc[i] = 0.f;
  int nk = K / 16;
#pragma unroll 4
  for (int kk = 0; kk < nk; ++kk) {
    short8 a = load_bf8(ap + kk * 16);
    short8 b = load_bf8(bp + kk * 16);
    acc = mfma32(a, b, acc);
  }
  int n = n0 + lo;
  float bn = bias[n];
#pragma unroll
  for (int g = 0; g < 4; ++g) {
#pragma unroll
    for (int rr = 0; rr < 4; ++rr) {
      int r = g * 4 + rr;
      int m = m0 + g * 8 + hi * 4 + rr;
      float v = acc[r] + bn;
      if (MODE == 0) {
        ((unsigned short*)out)[(size_t)m * N + n] = f2bf(v);
      } else if (MODE == 2) {
        ((float*)out)[(size_t)m * N + n] = v + resid[(size_t)m * N + n];
      } else {
        float sg = v / (1.0f + exp2h(-LOG2E * v));
        ((unsigned short*)out)[(size_t)m * N + n] = f2bf(sg);
      }
    }
  }
}

// ------------- flash cross-attention with geometry --------------------------
// grid: 32 q-tiles * NSPLIT; block: 4 waves = 4 heads. (round-1 structure)
__global__ __launch_bounds__(256)
void attn_kernel(const unsigned short* __restrict__ Qbf, const unsigned short* __restrict__ Kbf,
                 const unsigned short* __restrict__ VTbf,
                 const float* __restrict__ x_lig, const float* __restrict__ x_pocket,
                 const float* __restrict__ tabG,
                 unsigned* __restrict__ partOb, float4* __restrict__ partZC) {
  __shared__ float4 xch[CHUNK];            // 4 KB
  __shared__ float tab[NHEAD][NTAB];       // 16 KB

  int tid = threadIdx.x;
  int h = tid >> 6;
  int lane = tid & 63;
  int lo = lane & 31, hi = lane >> 5;
  int qt = blockIdx.x & 31;
  int split = blockIdx.x >> 5;
  int q0 = qt * 32;
  int j0g = split * CHUNK;

  for (int i = tid; i < CHUNK; i += 256) {
    float x = x_pocket[(j0g + i) * 3 + 0];
    float y = x_pocket[(j0g + i) * 3 + 1];
    float z = x_pocket[(j0g + i) * 3 + 2];
    float4 v; v.x = x; v.y = y; v.z = z; v.w = 0.f;
    xch[i] = v;
  }
  for (int i = tid; i < NHEAD * NTAB; i += 256) ((float*)tab)[i] = tabG[i];
  __syncthreads();

  int q = q0 + lo;
  float xl0 = x_lig[q * 3 + 0];
  float xl1 = x_lig[q * 3 + 1];
  float xl2 = x_lig[q * 3 + 2];

  short8 qfr[4];
#pragma unroll
  for (int kk = 0; kk < 4; ++kk)
    qfr[kk] = load_bf8(Qbf + (size_t)q * HIDDEN + h * HDIM + kk * 16 + hi * 8);

  f32x16 O0, O1;
#pragma unroll
  for (int i = 0; i < 16; ++i) { O0[i] = 0.f; O1[i] = 0.f; }
  float Z = 0.f, c0 = 0.f, c1 = 0.f, c2 = 0.f;

#pragma unroll 1
  for (int t = 0; t < CHUNK / 32; ++t) {
    int jb = t * 32;
    f32x16 s;
#pragma unroll
    for (int i = 0; i < 16; ++i) s[i] = 0.f;
#pragma unroll
    for (int kk = 0; kk < 4; ++kk) {
      short8 a = load_bf8(Kbf + (size_t)(j0g + jb + lo) * HIDDEN + h * HDIM + kk * 16 + hi * 8);
      s = mfma32(a, qfr[kk], s);
    }
    unsigned wp[8];
    float pprev = 0.f;
#pragma unroll
    for (int r = 0; r < 16; ++r) {
      int jl = (r & 3) + 8 * (r >> 2) + 4 * hi;
      float4 xp = xch[jb + jl];
      float dx = xp.x - xl0, dy = xp.y - xl1, dz = xp.z - xl2;
      float r2 = fmaf(dx, dx, fmaf(dy, dy, dz * dz));
      float r2c = fmaxf(r2, 1e-24f);
      float rinv = rsqh(r2c);
      float d = r2c * rinv;
      int idx = (int)(d * (NTAB / 10.0f));
      idx = idx > (NTAB - 1) ? (NTAB - 1) : idx;
      float b = tab[h][idx];
      float s2 = fmaf(s[r], QK_SCALE, b);
      float pe = (r2 < 100.0f) ? exp2h(s2) : 0.0f;
      Z += pe;
      float pr = pe * rinv;
      c0 = fmaf(pr, dx, c0);
      c1 = fmaf(pr, dy, c1);
      c2 = fmaf(pr, dz, c2);
      if (r & 1) wp[r >> 1] = cvtpk(pprev, pe); else pprev = pe;
    }
#pragma unroll
    for (int sub = 0; sub < 2; ++sub) {
      unsigned W0 = wp[sub * 4 + 0], W1 = wp[sub * 4 + 1];
      unsigned W2 = wp[sub * 4 + 2], W3 = wp[sub * 4 + 3];
      unsigned e01 = (unsigned)__shfl_xor((int)(hi ? W0 : W2), 32);
      unsigned e23 = (unsigned)__shfl_xor((int)(hi ? W1 : W3), 32);
      U4S8 pb;
      pb.u.x = hi ? e01 : W0;
      pb.u.y = hi ? e23 : W1;
      pb.u.z = hi ? W2 : e01;
      pb.u.w = hi ? W3 : e23;
      const unsigned short* vbase =
          VTbf + (size_t)(h * HDIM + lo) * NPOCK + j0g + jb + sub * 16 + hi * 8;
      short8 v0 = load_bf8(vbase);
      short8 v1 = load_bf8(vbase + (size_t)32 * NPOCK);
      O0 = mfma32(v0, pb.s, O0);
      O1 = mfma32(v1, pb.s, O1);
    }
  }

  // store flash partials as bf16: O^T rows d = g*8+hi*4+(0..3), col q = lo
  unsigned* po = partOb + (size_t)(((q * NHEAD) + h) * NSPLIT + split) * (HDIM / 2);
#pragma unroll
  for (int g = 0; g < 4; ++g) {
    uint2 u0;
    u0.x = cvtpk(O0[g * 4 + 0], O0[g * 4 + 1]);
    u0.y = cvtpk(O0[g * 4 + 2], O0[g * 4 + 3]);
    *(uint2*)(po + (g * 8 + hi * 4) / 2) = u0;
    uint2 u1;
    u1.x = cvtpk(O1[g * 4 + 0], O1[g * 4 + 1]);
    u1.y = cvtpk(O1[g * 4 + 2], O1[g * 4 + 3]);
    *(uint2*)(po + (32 + g * 8 + hi * 4) / 2) = u1;
  }
  float Zt = Z + __shfl_xor(Z, 32);
  float c0t = c0 + __shfl_xor(c0, 32);
  float c1t = c1 + __shfl_xor(c1, 32);
  float c2t = c2 + __shfl_xor(c2, 32);
  if (hi == 0) {
    float4 zc; zc.x = Zt; zc.y = c0t; zc.z = c1t; zc.w = c2t;
    partZC[((q * NHEAD) + h) * NSPLIT + split] = zc;
  }
}

// ------------- combine splits -> h_attended (bf16) + coord messages ---------
__global__ __launch_bounds__(256)
void combine_kernel(const unsigned short* __restrict__ partOb, const float4* __restrict__ partZC,
                    unsigned short* __restrict__ hattb, float* __restrict__ cmsg) {
  int q = blockIdx.x;
  int t = threadIdx.x;
  int h = t >> 6, dl = t & 63;
  float Zh = 0.f;
#pragma unroll
  for (int s = 0; s < NSPLIT; ++s) Zh += partZC[(q * NHEAD + h) * NSPLIT + s].x;
  float o = 0.f;
#pragma unroll
  for (int s = 0; s < NSPLIT; ++s)
    o += bf2f(partOb[(size_t)((q * NHEAD + h) * NSPLIT + s) * HDIM + dl]);
  float inv = (Zh > 0.f) ? 1.0f / Zh : 0.f;
  hattb[(size_t)q * HIDDEN + h * HDIM + dl] = f2bf(o * inv);

  __shared__ float sm[NHEAD][3];
  if (t < NHEAD) {
    float zz = 0.f, a0 = 0.f, a1 = 0.f, a2 = 0.f;
    for (int s = 0; s < NSPLIT; ++s) {
      float4 v = partZC[(q * NHEAD + t) * NSPLIT + s];
      zz += v.x; a0 += v.y; a1 += v.z; a2 += v.w;
    }
    float iv = (zz > 0.f) ? 0.25f / zz : 0.f;
    sm[t][0] = a0 * iv; sm[t][1] = a1 * iv; sm[t][2] = a2 * iv;
  }
  __syncthreads();
  if (t < 3) cmsg[q * 3 + t] = sm[0][t] + sm[1][t] + sm[2][t] + sm[3][t];
}

// ------------- coord scale dot + x_out --------------------------------------
__global__ __launch_bounds__(64)
void coord_kernel(const unsigned short* __restrict__ c1out, const float* __restrict__ c2w,
                  const float* __restrict__ c2b, const float* __restrict__ cmsg,
                  const float* __restrict__ x_lig, float* __restrict__ x_out) {
  int q = blockIdx.x;
  int lane = threadIdx.x;
  const unsigned short* row = c1out + (size_t)q * HIDDEN + lane * 4;
  ushort4 tv = *(const ushort4*)row;
  float4 wv = *(const float4*)(c2w + lane * 4);
  float acc = bf2f(tv.x) * wv.x + bf2f(tv.y) * wv.y + bf2f(tv.z) * wv.z + bf2f(tv.w) * wv.w;
#pragma unroll
  for (int m = 32; m >= 1; m >>= 1) acc += __shfl_xor(acc, m);
  if (lane == 0) {
    float sc = acc + c2b[0];
    x_out[q * 3 + 0] = x_lig[q * 3 + 0] + sc * cmsg[q * 3 + 0];
    x_out[q * 3 + 1] = x_lig[q * 3 + 1] + sc * cmsg[q * 3 + 1];
    x_out[q * 3 + 2] = x_lig[q * 3 + 2] + sc * cmsg[q * 3 + 2];
  }
}

extern "C" void kernel_launch(void* const* d_in, const int* in_sizes, int n_in,
                              void* d_out, int out_size, void* d_ws, size_t ws_size,
                              hipStream_t stream) {
  const float* h_lig  = (const float*)d_in[0];
  const float* x_lig  = (const float*)d_in[1];
  const float* h_atom = (const float*)d_in[2];
  const float* x_pock = (const float*)d_in[3];
  const float* qw  = (const float*)d_in[4];
  const float* qb  = (const float*)d_in[5];
  const float* kw  = (const float*)d_in[6];
  const float* kb  = (const float*)d_in[7];
  const float* vw  = (const float*)d_in[8];
  const float* vb  = (const float*)d_in[9];
  const float* ow  = (const float*)d_in[10];
  const float* ob  = (const float*)d_in[11];
  const float* e1w = (const float*)d_in[12];
  const float* e1b = (const float*)d_in[13];
  const float* e2w = (const float*)d_in[14];
  const float* e2b = (const float*)d_in[15];
  const float* c1w = (const float*)d_in[16];
  const float* c1b = (const float*)d_in[17];
  const float* c2w = (const float*)d_in[18];
  const float* c2b = (const float*)d_in[19];

  char* w = (char*)d_ws;
  unsigned short* hAb  = (unsigned short*)w; w += (size_t)NPOCK * ADIM * 2;
  unsigned short* hlb  = (unsigned short*)w; w += (size_t)NLIG * HIDDEN * 2;
  unsigned short* qwT  = (unsigned short*)w; w += 256 * 256 * 2;
  unsigned short* kwT  = (unsigned short*)w; w += 256 * 512 * 2;
  unsigned short* vwT  = (unsigned short*)w; w += 256 * 512 * 2;
  unsigned short* owT  = (unsigned short*)w; w += 256 * 256 * 2;
  unsigned short* c1wT = (unsigned short*)w; w += 256 * 256 * 2;
  unsigned short* Qb   = (unsigned short*)w; w += (size_t)NLIG * HIDDEN * 2;
  unsigned short* Kb   = (unsigned short*)w; w += (size_t)NPOCK * HIDDEN * 2;
  unsigned short* VTb  = (unsigned short*)w; w += (size_t)HIDDEN * NPOCK * 2;
  float* tabG          = (float*)w;          w += NHEAD * NTAB * 4;
  unsigned* partOb     = (unsigned*)w;       w += (size_t)NLIG * NHEAD * NSPLIT * HDIM * 2; // bf16
  float* partZC        = (float*)w;          w += (size_t)NLIG * NHEAD * NSPLIT * 4 * 4;
  unsigned short* hatt = (unsigned short*)w; w += (size_t)NLIG * HIDDEN * 2;
  unsigned short* c1o  = (unsigned short*)w; w += (size_t)NLIG * HIDDEN * 2;
  float* cmsg          = (float*)w;          w += (size_t)NLIG * 3 * 4;

  float* hout = (float*)d_out;
  float* xout = ((float*)d_out) + (size_t)NLIG * HIDDEN;

  prep_kernel<<<NCAST + NTRANS + NTAB / 4, 256, 0, stream>>>(
      h_atom, h_lig, qw, kw, vw, ow, c1w, e1w, e1b, e2w, e2b,
      hAb, hlb, qwT, kwT, vwT, owT, c1wT, tabG);
  kv_gemm_kernel<<<dim3(NPOCK / 128, HIDDEN / 32), 256, 0, stream>>>(
      hAb, kwT, vwT, kb, vb, Kb, VTb);
  gemm32_kernel<0><<<dim3(NLIG / 32, HIDDEN / 32), 64, 0, stream>>>(
      hlb, qwT, qb, (void*)Qb, nullptr, NLIG, HIDDEN, HIDDEN);
  attn_kernel<<<32 * NSPLIT, 256, 0, stream>>>(Qb, Kb, VTb, x_lig, x_pock, tabG,
                                               partOb, (float4*)partZC);
  combine_kernel<<<NLIG, 256, 0, stream>>>((const unsigned short*)partOb,
                                           (const float4*)partZC, hatt, cmsg);
  gemm32_kernel<2><<<dim3(NLIG / 32, HIDDEN / 32), 64, 0, stream>>>(
      hatt, owT, ob, (void*)hout, h_lig, NLIG, HIDDEN, HIDDEN);
  gemm32_kernel<3><<<dim3(NLIG / 32, HIDDEN / 32), 64, 0, stream>>>(
      hatt, c1wT, c1b, (void*)c1o, nullptr, NLIG, HIDDEN, HIDDEN);
  coord_kernel<<<NLIG, 64, 0, stream>>>(c1o, c2w, c2b, cmsg, x_lig, xout);
}